// Round 7
// baseline (1051.531 us; speedup 1.0000x reference)
//
#include <hip/hip_runtime.h>
#include <math.h>

// SoftSkeletonize via the erosion-chain identity:
//   e_0 = img, e_{i+1} = erode(e_i)      (erode = 5-pt cross min, +inf pad)
//   delta_i = relu(e_i - dilate3x3(e_{i+1}))            (dilate pad = -inf)
//   skel: s = delta_0; s += relu(delta_i - s*delta_i), i = 1..40
//
// 5 fused phases (S = 9,8,8,8,8). Per 64x64 tile, stage e with halo in LDS;
// S+1 merged passes per phase, single buffer, in-place chain (verified r8/r9).
//
// Round-10 (resubmitted round-11: round-10 bench hit GPUAcquisitionTimeout,
// kernel never measured). Evidence so far: wall time tracks LDS instruction
// count and nothing else (conflict counter ~= 4cyc/b128 intrinsic overhead;
// occupancy moves don't help; DPP trade lost to VALU). So: cut LDS
// instructions 2.4x by WIDENING the per-thread patch to 2x8 (one "oct"):
//  * per pass: 4 b128 (U,D) + 4 b32 edges (+4 b32 cw edges) + 4 b128 writes
//    vs (per same area) 12 b128 + 8 b128 + 4 b128. Single-scalar edges now
//    use ds_read_b32 (~5.8 cyc) not wasted b128 (~12 cyc).
//  * MTC=16 -> 96 data cols = 12 octs -> NIDX = 42x12 = 504 = ONE round
//    (no q-loop; persistent state halves vs r5's two-round arrays).
//  * padded-oct layout: each oct stored in 12 floats (8 data + 4 pad) ->
//    lane stride 3 quads (odd) -> 8 consecutive lanes cover all 8 quad-banks
//    -> conflict-free b128. Pads are NEVER read (reads are oct-aligned b128
//    or exact-float b32). Row stride 144 floats.
//  * LDS 86*144*4 = 48.4 KB single buffer; in-place: read -> compute in regs
//    -> barrier -> store own rows -> barrier (r8-verified).
//  * shrinking window kept (oct-floored bounds only widen; r8-verified).
//  * __launch_bounds__(512,4) ONLY (r7/r8 rule: forcing min-occupancy spills).

#define HH 1024
#define WW 1024
#define T 64
#define MTR 11                 // top row margin (central rows = buf rows 11..74)
#define MTC 16                 // left col margin (central cols = data cols 16..79)
#define RH 86                  // buffer rows
#define OCT 12                 // octs per row (96 data cols)
#define RSTRD 144              // floats per buffer row (12 octs x 12 floats)
#define NT 512
#define NIDX 504               // 42 row-pairs x 12 octs

#define LD4(p)    (*(const float4*)(p))
#define ST4(p, v) (*(float4*)(p) = (v))

__device__ __forceinline__ float relu_(float x) { return x > 0.f ? x : 0.f; }
__device__ __forceinline__ float4 min4_(float4 a, float4 b) {
    return make_float4(fminf(a.x,b.x), fminf(a.y,b.y), fminf(a.z,b.z), fminf(a.w,b.w));
}
__device__ __forceinline__ float4 max4_(float4 a, float4 b) {
    return make_float4(fmaxf(a.x,b.x), fmaxf(a.y,b.y), fmaxf(a.z,b.z), fmaxf(a.w,b.w));
}
// 3-tap horizontal min/max of quad a with scalar edges L (col-1), R (col+4)
__device__ __forceinline__ float4 hmin4(float L, float4 a, float R) {
    float4 h;
    h.x = fminf(L,   fminf(a.x, a.y)); h.y = fminf(a.x, fminf(a.y, a.z));
    h.z = fminf(a.y, fminf(a.z, a.w)); h.w = fminf(a.z, fminf(a.w, R));
    return h;
}
__device__ __forceinline__ float4 hmax4(float L, float4 a, float R) {
    float4 h;
    h.x = fmaxf(L,   fmaxf(a.x, a.y)); h.y = fmaxf(a.x, fmaxf(a.y, a.z));
    h.z = fmaxf(a.y, fmaxf(a.z, a.w)); h.w = fmaxf(a.z, fmaxf(a.w, R));
    return h;
}
__device__ __forceinline__ float4 dmask4(float4 v, float rm, float4 cm) {
    // keep if in-image (rm/cm = +INF), else -INF (rm/cm = -INF)
    float4 o;
    o.x = fminf(fminf(v.x, cm.x), rm); o.y = fminf(fminf(v.y, cm.y), rm);
    o.z = fminf(fminf(v.z, cm.z), rm); o.w = fminf(fminf(v.w, cm.w), rm);
    return o;
}
__device__ __forceinline__ void skup(float4& s, float4 e, float4 d, bool init) {
    float4 dl;
    dl.x = relu_(e.x - d.x); dl.y = relu_(e.y - d.y);
    dl.z = relu_(e.z - d.z); dl.w = relu_(e.w - d.w);
    if (init) { s = dl; }
    else {
        s.x += relu_(dl.x - s.x * dl.x); s.y += relu_(dl.y - s.y * dl.y);
        s.z += relu_(dl.z - s.z * dl.z); s.w += relu_(dl.w - s.w * dl.w);
    }
}
// column mask quad for 4 consecutive cols starting at g (erode: -inf in, +inf out)
__device__ __forceinline__ float4 cmask_er(int g) {
    float4 m;
    m.x = (unsigned)(g + 0) < WW ? -INFINITY : INFINITY;
    m.y = (unsigned)(g + 1) < WW ? -INFINITY : INFINITY;
    m.z = (unsigned)(g + 2) < WW ? -INFINITY : INFINITY;
    m.w = (unsigned)(g + 3) < WW ? -INFINITY : INFINITY;
    return m;
}
// column mask quad (dilate: +inf in, -inf out)
__device__ __forceinline__ float4 cmask_dl(int g) {
    float4 m;
    m.x = (unsigned)(g + 0) < WW ? INFINITY : -INFINITY;
    m.y = (unsigned)(g + 1) < WW ? INFINITY : -INFINITY;
    m.z = (unsigned)(g + 2) < WW ? INFINITY : -INFINITY;
    m.w = (unsigned)(g + 3) < WW ? INFINITY : -INFINITY;
    return m;
}

__global__ __launch_bounds__(NT, 4) void phase_kernel(
    const float* __restrict__ src, float* __restrict__ dst,
    float* __restrict__ skel, int S, int first, int last)
{
    __shared__ __align__(16) float buf[RH * RSTRD + 4];

    const int h0 = blockIdx.y * T;
    const int w0 = blockIdx.x * T;
    const size_t plane = (size_t)HH * WW;
    const float* sp = src + blockIdx.z * plane;
    float* skp = skel + blockIdx.z * plane;
    float* dp = dst ? dst + blockIdx.z * plane : nullptr;

    const int tid = threadIdx.x;
    const bool border = (h0 == 0) || (w0 == 0) || (h0 + T == HH) || (w0 + T == WW);

    // ---- stage e_{i0} (+inf outside image); pads (floats 8..11 of each oct)
    //      are left undefined -- they are never read.
    if (!border) {
        const float* base = sp + (size_t)(h0 - MTR) * WW + (w0 - MTC);
        for (int i = tid; i < RH * 2 * OCT; i += NT) {     // 2 quads per oct
            int r = i / (2 * OCT), k = i - r * (2 * OCT);
            int j = k >> 1, h = (k & 1) << 2;              // h = 0 or 4
            ST4(&buf[r * RSTRD + 12 * j + h], LD4(base + (size_t)r * WW + 8 * j + h));
        }
    } else {
        for (int i = tid; i < RH * 96; i += NT) {
            int r = i / 96, cc = i - r * 96;
            int gh = h0 - MTR + r, gw = w0 - MTC + cc;
            float v = INFINITY;
            if ((unsigned)gh < HH && (unsigned)gw < WW) v = sp[(size_t)gh * WW + gw];
            buf[r * RSTRD + 12 * (cc >> 3) + (cc & 7)] = v;
        }
    }

    // ---- geometry: thread owns a 2-row x 8-col patch (one oct wide)
    const bool act = (tid < NIDX);
    const int p = tid / OCT, j = tid - OCT * p;            // row-pair, oct-col
    const int o = (1 + 2 * p) * RSTRD + 12 * j;            // own float offset
    const bool cen = act && (p >= 5) && (p <= 36) && (j >= 2) && (j <= 9);

    float4 sL0, sR0, sL1, sR1;            // skel accumulators (2 rows x 8)
    float4 aL0, aR0, aL1, aR1;            // e_{t-1} own patch (registers)
    float4 pL0, pR0, pL1, pR1;            // e_{t-2} own patch (registers)
    if (!first && cen) {
        const float* g = skp + (size_t)(h0 + 2 * p - 10) * WW + (w0 + 8 * j - 16);
        sL0 = LD4(g);      sR0 = LD4(g + 4);
        sL1 = LD4(g + WW); sR1 = LD4(g + WW + 4);
    }
    __syncthreads();

    if (act) {
        aL0 = LD4(buf + o);          aR0 = LD4(buf + o + 4);
        aL1 = LD4(buf + o + RSTRD);  aR1 = LD4(buf + o + RSTRD + 4);
    }

    for (int t = 1; t <= S + 1; ++t) {
        const int mt = S + 1 - t;            // validity margin needed after pass t
        const bool do_er = (t <= S);
        const bool do_dl = (t >= 2);
        const bool init = (first != 0) && (t == 2);
        // shrinking active window (== cen at mt = 0); oct-floored bounds only widen
        const int plo = (mt >= 10) ? 0 : ((10 - mt) >> 1);
        const int phi_ = (73 + mt) >> 1;  const int phi = phi_ > 41 ? 41 : phi_;
        const int jlo = (mt >= 16) ? 0 : ((16 - mt) >> 3);
        const int jhi_ = (79 + mt) >> 3;  const int jhi = jhi_ > 11 ? 11 : jhi_;
        bool wr = false;
        const bool inw = act && (p >= plo) && (p <= phi) && (j >= jlo) && (j <= jhi);
        const bool cw = cen && do_dl;
        if (inw && (do_er || cw)) {
            // LDS reads: vertical oct pairs + 4 scalar edges (+4 cw edges)
            float4 UL = LD4(buf + o - RSTRD), UR = LD4(buf + o - RSTRD + 4);
            float4 DL = LD4(buf + o + 2 * RSTRD), DR = LD4(buf + o + 2 * RSTRD + 4);
            float eAm = buf[o - 5],          eAp = buf[o + 12];          // row r edges
            float eBm = buf[o + RSTRD - 5],  eBp = buf[o + RSTRD + 12];  // row r+1
            float mUm = 0.f, mUp = 0.f, mDm = 0.f, mDp = 0.f;
            if (cw) {
                mUm = buf[o - RSTRD - 5];     mUp = buf[o - RSTRD + 12];
                mDm = buf[o + 2 * RSTRD - 5]; mDp = buf[o + 2 * RSTRD + 12];
            }
            float4 e0L, e0R, e1L, e1R;
            if (do_er) {
                float4 hL0 = hmin4(eAm, aL0, aR0.x), hR0 = hmin4(aL0.w, aR0, eAp);
                float4 hL1 = hmin4(eBm, aL1, aR1.x), hR1 = hmin4(aL1.w, aR1, eBp);
                e0L = min4_(min4_(UL, aL1), hL0); e0R = min4_(min4_(UR, aR1), hR0);
                e1L = min4_(min4_(aL0, DL), hL1); e1R = min4_(min4_(aR0, DR), hR1);
                if (border) {   // force +inf outside image
                    int ghb = h0 - MTR + 1 + 2 * p;
                    int gwb = w0 - MTC + 8 * j;
                    float4 cmL = cmask_er(gwb), cmR = cmask_er(gwb + 4);
                    float r0 = (unsigned)ghb       < HH ? -INFINITY : INFINITY;
                    float r1 = (unsigned)(ghb + 1) < HH ? -INFINITY : INFINITY;
                    float4 r0v = make_float4(r0, r0, r0, r0);
                    float4 r1v = make_float4(r1, r1, r1, r1);
                    e0L = max4_(e0L, max4_(r0v, cmL)); e0R = max4_(e0R, max4_(r0v, cmR));
                    e1L = max4_(e1L, max4_(r1v, cmL)); e1R = max4_(e1R, max4_(r1v, cmR));
                }
                wr = true;
            }
            if (cw) {
                float4 tUL = UL, tUR = UR, tAL = aL0, tAR = aR0;
                float4 tBL = aL1, tBR = aR1, tDL = DL, tDR = DR;
                float dUm = mUm, dUp = mUp, dAm = eAm, dAp = eAp;
                float dBm = eBm, dBp = eBp, dDm = mDm, dDp = mDp;
                if (border) {   // force -inf outside image before hmax
                    int ghb = h0 - MTR + 1 + 2 * p;
                    int gwb = w0 - MTC + 8 * j;
                    float rm0 = (unsigned)(ghb - 1) < HH ? INFINITY : -INFINITY;
                    float rm1 = (unsigned)(ghb)     < HH ? INFINITY : -INFINITY;
                    float rm2 = (unsigned)(ghb + 1) < HH ? INFINITY : -INFINITY;
                    float rm3 = (unsigned)(ghb + 2) < HH ? INFINITY : -INFINITY;
                    float cmL = (unsigned)(gwb - 1) < WW ? INFINITY : -INFINITY;
                    float cmR = (unsigned)(gwb + 8) < WW ? INFINITY : -INFINITY;
                    float4 dcL = cmask_dl(gwb), dcR = cmask_dl(gwb + 4);
                    tUL = dmask4(tUL, rm0, dcL); tUR = dmask4(tUR, rm0, dcR);
                    tAL = dmask4(tAL, rm1, dcL); tAR = dmask4(tAR, rm1, dcR);
                    tBL = dmask4(tBL, rm2, dcL); tBR = dmask4(tBR, rm2, dcR);
                    tDL = dmask4(tDL, rm3, dcL); tDR = dmask4(tDR, rm3, dcR);
                    dUm = fminf(fminf(dUm, cmL), rm0); dUp = fminf(fminf(dUp, cmR), rm0);
                    dAm = fminf(fminf(dAm, cmL), rm1); dAp = fminf(fminf(dAp, cmR), rm1);
                    dBm = fminf(fminf(dBm, cmL), rm2); dBp = fminf(fminf(dBp, cmR), rm2);
                    dDm = fminf(fminf(dDm, cmL), rm3); dDp = fminf(fminf(dDp, cmR), rm3);
                }
                float4 hUL = hmax4(dUm, tUL, tUR.x), hUR = hmax4(tUL.w, tUR, dUp);
                float4 hAL = hmax4(dAm, tAL, tAR.x), hAR = hmax4(tAL.w, tAR, dAp);
                float4 hBL = hmax4(dBm, tBL, tBR.x), hBR = hmax4(tBL.w, tBR, dBp);
                float4 hDL = hmax4(dDm, tDL, tDR.x), hDR = hmax4(tDL.w, tDR, dDp);
                float4 d0L = max4_(hUL, max4_(hAL, hBL));
                float4 d0R = max4_(hUR, max4_(hAR, hBR));
                float4 d1L = max4_(hAL, max4_(hBL, hDL));
                float4 d1R = max4_(hAR, max4_(hBR, hDR));
                skup(sL0, pL0, d0L, init); skup(sR0, pR0, d0R, init);
                skup(sL1, pL1, d1L, init); skup(sR1, pR1, d1R, init);
            }
            if (do_er) {   // rotate AFTER dilate/skup consumed e_{t-2}
                pL0 = aL0; pR0 = aR0; pL1 = aL1; pR1 = aR1;
                aL0 = e0L; aR0 = e0R; aL1 = e1L; aR1 = e1R;
            }
        }
        if (do_er) {
            __syncthreads();   // all reads of e_{t-1} complete
            if (wr) {
                ST4(buf + o, aL0);          ST4(buf + o + 4, aR0);
                ST4(buf + o + RSTRD, aL1);  ST4(buf + o + RSTRD + 4, aR1);
            }
            __syncthreads();   // e_t visible for next pass
        }
    }

    // ---- writeback: skel always; e_S central (from registers) if not last phase
    if (cen) {
        size_t grow = (size_t)(h0 + 2 * p - 10) * WW + (w0 + 8 * j - 16);
        ST4(skp + grow, sL0);      ST4(skp + grow + 4, sR0);
        ST4(skp + grow + WW, sL1); ST4(skp + grow + WW + 4, sR1);
        if (!last) {
            ST4(dp + grow, aL0);      ST4(dp + grow + 4, aR0);
            ST4(dp + grow + WW, aL1); ST4(dp + grow + WW + 4, aR1);
        }
    }
}

extern "C" void kernel_launch(void* const* d_in, const int* in_sizes, int n_in,
                              void* d_out, int out_size, void* d_ws, size_t ws_size,
                              hipStream_t stream) {
    const float* img = (const float*)d_in[0];
    float* skel = (float*)d_out;
    const int B = in_sizes[0] / (HH * WW);  // 16
    const size_t plane = (size_t)HH * WW;

    float* e0 = (float*)d_ws;
    float* e1 = e0 + (size_t)B * plane;

    dim3 grid(WW / T, HH / T, B);
    dim3 block(NT);

    const int Ks[5] = {9, 8, 8, 8, 8};   // 41 deltas total (init + 40 iters)
    const float* src = img;
    float* ebufs[2] = {e0, e1};
    for (int p = 0; p < 5; ++p) {
        int first = (p == 0), last = (p == 4);
        float* dstp = last ? nullptr : ebufs[p & 1];
        phase_kernel<<<grid, block, 0, stream>>>(src, dstp, skel, Ks[p], first, last);
        src = dstp;
    }
}

// Round 8
// 986.290 us; speedup vs baseline: 1.0661x; 1.0661x over previous
//
#include <hip/hip_runtime.h>
#include <math.h>

// SoftSkeletonize via the erosion-chain identity:
//   e_0 = img, e_{i+1} = erode(e_i)      (erode = 5-pt cross min, +inf pad)
//   delta_i = relu(e_i - dilate3x3(e_{i+1}))            (dilate pad = -inf)
//   skel: s = delta_0; s += relu(delta_i - s*delta_i), i = 1..40
//
// 5 fused phases (S = 9,8,8,8,8). Per 64x64 tile, stage e with halo
// (11 rows / 12 cols) in LDS; S+1 merged passes per phase, DOUBLE buffer
// (1 barrier/pass -- measured 20us/dispatch cheaper than in-place 2-barrier).
//
// Round-12 = round-5 champion (956us, 207us/dispatch) + shrinking window.
// Evidence from r9-r11: wall time in the 207-229us regime tracks BARRIER
// COUNT, not LDS op count (r9 all-b128 20 ops/pass == oct 12 ops/pass ==
// 225-229us, both 2 barriers/pass; r5 champion 1 barrier/pass = 207us).
// b32 edges at even dword lane-stride are 8-way bank-conflicted (m136) --
// the oct kernel's "savings" were eaten by exactly that. So: keep the
// champion structure byte-for-byte and add the ONE verified-correct
// component it lacks:
//  * shrinking active window (r8/r9/r10-verified, absmax 0.0): pass t needs
//    validity margin mt = S+1-t; threads whose 2x4 patch misses image+-mt
//    skip the pass entirely (~9-10%% fewer lane-ops in BOTH pipes).
//    Double-buffer validity: reads at t+1 span +-(m_{t+1}+1) = +-mt; every
//    cell in +-mt belongs to a patch intersecting +-mt -> windowed-in at t
//    -> freshly written to db. cen (subset of) window at all t.
// Stride 92 floats (23 quads): all b128 accesses bank-conflict-free.
// Own-patch rows register-resident (a0r/a1r = e_{t-1}, ep0/ep1 = e_{t-2}).
// __launch_bounds__(512,4) ONLY (r7/r8 rule: forcing min-occupancy spills).

#define HH 1024
#define WW 1024
#define T 64
#define MTR 11                 // top row margin  (central rows start at buf row 11)
#define MTC 12                 // left col margin (central cols start at quad 3)
#define RH 86                  // buffer rows
#define STq 22                 // worker quad-cols per row
#define STGQ 23                // staged quads per row (fills the 92-float row)
#define STRD 92                // floats per buffer row (23 quads -> conflict-free b128)
#define NT 512
#define NIDX 924               // 42 row-pairs x 22 quad-cols

#define LD4(p)    (*(const float4*)(p))
#define ST4(p, v) (*(float4*)(p) = (v))

__device__ __forceinline__ float relu_(float x) { return x > 0.f ? x : 0.f; }
__device__ __forceinline__ float4 min4_(float4 a, float4 b) {
    return make_float4(fminf(a.x,b.x), fminf(a.y,b.y), fminf(a.z,b.z), fminf(a.w,b.w));
}
__device__ __forceinline__ float4 max4_(float4 a, float4 b) {
    return make_float4(fmaxf(a.x,b.x), fmaxf(a.y,b.y), fmaxf(a.z,b.z), fmaxf(a.w,b.w));
}
// 3-tap horizontal min/max of quad a with scalar edges L (col-1), R (col+4)
__device__ __forceinline__ float4 hmin4(float L, float4 a, float R) {
    float4 h;
    h.x = fminf(L,   fminf(a.x, a.y)); h.y = fminf(a.x, fminf(a.y, a.z));
    h.z = fminf(a.y, fminf(a.z, a.w)); h.w = fminf(a.z, fminf(a.w, R));
    return h;
}
__device__ __forceinline__ float4 hmax4(float L, float4 a, float R) {
    float4 h;
    h.x = fmaxf(L,   fmaxf(a.x, a.y)); h.y = fmaxf(a.x, fmaxf(a.y, a.z));
    h.z = fmaxf(a.y, fmaxf(a.z, a.w)); h.w = fmaxf(a.z, fmaxf(a.w, R));
    return h;
}
__device__ __forceinline__ float4 dmask4(float4 v, float rm, float4 cm) {
    // keep if in-image (rm/cm = +INF), else -INF (rm/cm = -INF)
    float4 o;
    o.x = fminf(fminf(v.x, cm.x), rm); o.y = fminf(fminf(v.y, cm.y), rm);
    o.z = fminf(fminf(v.z, cm.z), rm); o.w = fminf(fminf(v.w, cm.w), rm);
    return o;
}
__device__ __forceinline__ void skup(float4& s, float4 e, float4 d, bool init) {
    float4 dl;
    dl.x = relu_(e.x - d.x); dl.y = relu_(e.y - d.y);
    dl.z = relu_(e.z - d.z); dl.w = relu_(e.w - d.w);
    if (init) { s = dl; }
    else {
        s.x += relu_(dl.x - s.x * dl.x); s.y += relu_(dl.y - s.y * dl.y);
        s.z += relu_(dl.z - s.z * dl.z); s.w += relu_(dl.w - s.w * dl.w);
    }
}

__global__ __launch_bounds__(NT, 4) void phase_kernel(
    const float* __restrict__ src, float* __restrict__ dst,
    float* __restrict__ skel, int S, int first, int last)
{
    __shared__ __align__(16) float buf0[RH * STRD + 4];
    __shared__ __align__(16) float buf1[RH * STRD + 4];

    const int h0 = blockIdx.y * T;
    const int w0 = blockIdx.x * T;
    const size_t plane = (size_t)HH * WW;
    const float* sp = src + blockIdx.z * plane;
    float* skp = skel + blockIdx.z * plane;
    float* dp = dst ? dst + blockIdx.z * plane : nullptr;

    const int tid = threadIdx.x;
    const bool border = (h0 == 0) || (w0 == 0) || (h0 + T == HH) || (w0 + T == WW);

    // ---- stage e_{i0} (+inf outside image) into buf0
    if (!border) {
        const float* base = sp + (size_t)(h0 - MTR) * WW + (w0 - MTC);
        for (int i = tid; i < RH * STGQ; i += NT) {
            int r = i / STGQ, q = i - r * STGQ;
            ST4(&buf0[r * STRD + 4 * q], LD4(base + (size_t)r * WW + 4 * q));
        }
    } else {
        for (int i = tid; i < RH * STRD; i += NT) {
            int r = i / STRD, c = i - r * STRD;
            int gh = h0 - MTR + r, gw = w0 - MTC + c;
            float v = INFINITY;
            if ((unsigned)gh < HH && (unsigned)gw < WW) v = sp[(size_t)gh * WW + gw];
            buf0[r * STRD + c] = v;
        }
    }

    // ---- per-round geometry (round q handles idx = tid + NT*q)
    int pq[2], cq[2], oq[2];
    bool act[2], cen[2];
    float4 s0[2], s1[2];
    float4 a0r[2], a1r[2];   // e_{t-1} at own 2 rows (register-resident)
    float4 ep0[2], ep1[2];   // e_{t-2} at own 2 rows (register-resident)
#pragma unroll
    for (int q = 0; q < 2; ++q) {
        int idx = tid + NT * q;
        act[q] = (idx < NIDX);
        int p = idx / STq, c = idx - STq * p;
        pq[q] = p; cq[q] = c;
        oq[q] = act[q] ? (1 + 2 * p) * STRD + 4 * c : STRD;
        cen[q] = act[q] && (p >= 5) && (p <= 36) && (c >= 3) && (c <= 18);
    }
    if (!first) {
#pragma unroll
        for (int q = 0; q < 2; ++q) if (cen[q]) {
            const float* g = skp + (size_t)(h0 + 2 * pq[q] - 10) * WW + (w0 + 4 * cq[q] - 12);
            s0[q] = LD4(g); s1[q] = LD4(g + WW);
        }
    }
    __syncthreads();

    // ---- init register-resident own rows from staged e_{i0}
#pragma unroll
    for (int q = 0; q < 2; ++q) if (act[q]) {
        a0r[q] = LD4(buf0 + oq[q]);
        a1r[q] = LD4(buf0 + oq[q] + STRD);
    }

    for (int t = 1; t <= S + 1; ++t) {
        float* sb = ((t - 1) & 1) ? buf1 : buf0;
        float* db = (t & 1) ? buf1 : buf0;
        const int mt = S + 1 - t;            // validity margin required after this pass
        const bool do_er = (t <= S);
        const bool do_dl = (t >= 2);
        const bool init = (first != 0) && (t == 2);
        // shrinking active window (== cen bounds at mt = 0)
        const int plo = (mt >= 9) ? 0 : ((10 - mt) >> 1);
        const int phi = (73 + mt) >> 1;      // <= 41 for mt <= 9
        const int clo = (mt >= 9) ? 0 : ((12 - mt) >> 2);
        const int chi = (75 + mt) >> 2;      // <= 21 for mt <= 9
#pragma unroll
        for (int q = 0; q < 2; ++q) {
            if (!act[q]) continue;
            if (pq[q] < plo || pq[q] > phi || cq[q] < clo || cq[q] > chi) continue;
            const bool cw = cen[q] && do_dl;
            if (!(do_er || cw)) continue;
            const int o = oq[q];
            // shared loads (erode rows r-1..r+2, mid rows with +/-4)
            float4 U   = LD4(sb + o - STRD);
            float4 Am0 = LD4(sb + o - 4);
            float4 Ap0 = LD4(sb + o + 4);
            float4 Am1 = LD4(sb + o + STRD - 4);
            float4 Ap1 = LD4(sb + o + STRD + 4);
            float4 D   = LD4(sb + o + 2 * STRD);
            float4 A0 = a0r[q], A1 = a1r[q];
            float4 Um, Up, Dm, Dp;
            if (cw) {   // extra edges for dilate rows r-1, r+2
                Um = LD4(sb + o - STRD - 4);
                Up = LD4(sb + o - STRD + 4);
                Dm = LD4(sb + o + 2 * STRD - 4);
                Dp = LD4(sb + o + 2 * STRD + 4);
            }
            float4 e0, e1;
            if (do_er) {
                float4 h0q = hmin4(Am0.w, A0, Ap0.x);
                float4 h1q = hmin4(Am1.w, A1, Ap1.x);
                e0 = min4_(min4_(U, A1), h0q);   // min(row r-1, row r+1, hmin row r)
                e1 = min4_(min4_(A0, D), h1q);
                if (border) {   // force +inf outside image
                    int ghb = h0 - MTR + 1 + 2 * pq[q];
                    int gwb = w0 - MTC + 4 * cq[q];
                    float4 cwm;
                    cwm.x = (unsigned)(gwb + 0) < WW ? -INFINITY : INFINITY;
                    cwm.y = (unsigned)(gwb + 1) < WW ? -INFINITY : INFINITY;
                    cwm.z = (unsigned)(gwb + 2) < WW ? -INFINITY : INFINITY;
                    cwm.w = (unsigned)(gwb + 3) < WW ? -INFINITY : INFINITY;
                    float r0 = (unsigned)ghb       < HH ? -INFINITY : INFINITY;
                    float r1 = (unsigned)(ghb + 1) < HH ? -INFINITY : INFINITY;
                    e0 = max4_(e0, max4_(make_float4(r0, r0, r0, r0), cwm));
                    e1 = max4_(e1, max4_(make_float4(r1, r1, r1, r1), cwm));
                }
                ST4(db + o, e0);
                ST4(db + o + STRD, e1);
            }
            if (cw) {
                float4 tU = U, tA = A0, tB = A1, tD = D;
                float eUm = Um.w, eUp = Up.x, eAm = Am0.w, eAp = Ap0.x;
                float eBm = Am1.w, eBp = Ap1.x, eDm = Dm.w, eDp = Dp.x;
                if (border) {   // force -inf outside image before hmax
                    int ghb = h0 - MTR + 1 + 2 * pq[q];
                    int gwb = w0 - MTC + 4 * cq[q];
                    float rm0 = (unsigned)(ghb - 1) < HH ? INFINITY : -INFINITY;
                    float rm1 = (unsigned)(ghb)     < HH ? INFINITY : -INFINITY;
                    float rm2 = (unsigned)(ghb + 1) < HH ? INFINITY : -INFINITY;
                    float rm3 = (unsigned)(ghb + 2) < HH ? INFINITY : -INFINITY;
                    float cmL = (unsigned)(gwb - 1) < WW ? INFINITY : -INFINITY;
                    float cmR = (unsigned)(gwb + 4) < WW ? INFINITY : -INFINITY;
                    float4 cmC;
                    cmC.x = (unsigned)(gwb + 0) < WW ? INFINITY : -INFINITY;
                    cmC.y = (unsigned)(gwb + 1) < WW ? INFINITY : -INFINITY;
                    cmC.z = (unsigned)(gwb + 2) < WW ? INFINITY : -INFINITY;
                    cmC.w = (unsigned)(gwb + 3) < WW ? INFINITY : -INFINITY;
                    tU = dmask4(tU, rm0, cmC); tA = dmask4(tA, rm1, cmC);
                    tB = dmask4(tB, rm2, cmC); tD = dmask4(tD, rm3, cmC);
                    eUm = fminf(fminf(eUm, cmL), rm0); eUp = fminf(fminf(eUp, cmR), rm0);
                    eAm = fminf(fminf(eAm, cmL), rm1); eAp = fminf(fminf(eAp, cmR), rm1);
                    eBm = fminf(fminf(eBm, cmL), rm2); eBp = fminf(fminf(eBp, cmR), rm2);
                    eDm = fminf(fminf(eDm, cmL), rm3); eDp = fminf(fminf(eDp, cmR), rm3);
                }
                float4 hU = hmax4(eUm, tU, eUp);
                float4 hA = hmax4(eAm, tA, eAp);
                float4 hB = hmax4(eBm, tB, eBp);
                float4 hD = hmax4(eDm, tD, eDp);
                float4 d0 = max4_(hU, max4_(hA, hB));
                float4 d1 = max4_(hA, max4_(hB, hD));
                skup(s0[q], ep0[q], d0, init);   // e_{t-2} from registers
                skup(s1[q], ep1[q], d1, init);
            }
            if (do_er) {   // rotate AFTER dilate/skup consumed e_{t-2}
                ep0[q] = A0; ep1[q] = A1;
                a0r[q] = e0; a1r[q] = e1;
            }
        }
        __syncthreads();
    }

    // ---- writeback: skel always; e_S central (from registers) if not last phase
#pragma unroll
    for (int q = 0; q < 2; ++q) if (cen[q]) {
        size_t grow = (size_t)(h0 + 2 * pq[q] - 10) * WW + (w0 + 4 * cq[q] - 12);
        ST4(skp + grow, s0[q]);
        ST4(skp + grow + WW, s1[q]);
        if (!last) {
            ST4(dp + grow, a0r[q]);
            ST4(dp + grow + WW, a1r[q]);
        }
    }
}

extern "C" void kernel_launch(void* const* d_in, const int* in_sizes, int n_in,
                              void* d_out, int out_size, void* d_ws, size_t ws_size,
                              hipStream_t stream) {
    const float* img = (const float*)d_in[0];
    float* skel = (float*)d_out;
    const int B = in_sizes[0] / (HH * WW);  // 16
    const size_t plane = (size_t)HH * WW;

    float* e0 = (float*)d_ws;
    float* e1 = e0 + (size_t)B * plane;

    dim3 grid(WW / T, HH / T, B);
    dim3 block(NT);

    const int Ks[5] = {9, 8, 8, 8, 8};   // 41 deltas total (init + 40 iters)
    const float* src = img;
    float* ebufs[2] = {e0, e1};
    for (int p = 0; p < 5; ++p) {
        int first = (p == 0), last = (p == 4);
        float* dstp = last ? nullptr : ebufs[p & 1];
        phase_kernel<<<grid, block, 0, stream>>>(src, dstp, skel, Ks[p], first, last);
        src = dstp;
    }
}